// Round 1
// baseline (10496.836 us; speedup 1.0000x reference)
//
#include <hip/hip_runtime.h>
#include <hip/hip_bf16.h>
#include <math.h>

#define B_   2
#define S_   4096
#define D_   768
#define H_   12
#define DH_  64
#define BS_  16
#define NB_  256
#define FF_  3072
#define BT_  (B_ * S_)          // 8192 token rows
#define SCALE_F 0.125f          // 1/sqrt(64)

// ---------------------------------------------------------------------------
// Embedding gather: x[row][d] = embed[ids[row]][d]
// ---------------------------------------------------------------------------
__global__ __launch_bounds__(256) void embed_kernel(
    const int* __restrict__ ids, const float* __restrict__ emb,
    float* __restrict__ x)
{
    int row = blockIdx.x;
    int id = ids[row];
    const float* src = emb + (size_t)id * D_;
    float* dst = x + (size_t)row * D_;
    for (int d = threadIdx.x; d < D_; d += 256) dst[d] = src[d];
}

// ---------------------------------------------------------------------------
// Tiled fp32 GEMM: C[M,N] = A[M,K] @ W[K,N] + bias[N]   (act: 0=none, 1=gelu)
// 128x128 tile, BK=16, 256 threads, 8x8 per thread.
// All shapes here are multiples of 128/16 -> no bounds checks.
// ---------------------------------------------------------------------------
#define TBM 128
#define TBN 128
#define TBK 16

__device__ __forceinline__ float gelu_tanh(float v)
{
    float v3 = v * v * v;
    return 0.5f * v * (1.0f + tanhf(0.79788456080286535588f * (v + 0.044715f * v3)));
}

__global__ __launch_bounds__(256) void gemm_f32(
    const float* __restrict__ A, const float* __restrict__ W,
    const float* __restrict__ bias, float* __restrict__ C,
    int M, int N, int K, int act)
{
    __shared__ float As[TBK][TBM + 1];
    __shared__ float Bs[TBK][TBN + 1];

    int bm = blockIdx.y * TBM;
    int bn = blockIdx.x * TBN;
    int t  = threadIdx.x;
    int tx = t & 15;       // 0..15
    int ty = t >> 4;       // 0..15

    float acc[8][8];
#pragma unroll
    for (int i = 0; i < 8; ++i)
#pragma unroll
        for (int j = 0; j < 8; ++j) acc[i][j] = 0.f;

    for (int k0 = 0; k0 < K; k0 += TBK) {
        // A tile: 128 rows x 16 k  (thread: m = t/16 + 16r, k = t%16)
#pragma unroll
        for (int r = 0; r < 8; ++r) {
            int m = (t >> 4) + 16 * r;
            int k = t & 15;
            As[k][m] = A[(size_t)(bm + m) * K + k0 + k];
        }
        // B tile: 16 k x 128 n  (thread: n = t%128, k = t/128 + 2r)
#pragma unroll
        for (int r = 0; r < 8; ++r) {
            int k = (t >> 7) + 2 * r;
            int n = t & 127;
            Bs[k][n] = W[(size_t)(k0 + k) * N + bn + n];
        }
        __syncthreads();
#pragma unroll
        for (int kk = 0; kk < TBK; ++kk) {
            float a[8], b[8];
#pragma unroll
            for (int i = 0; i < 8; ++i) a[i] = As[kk][ty * 8 + i];
#pragma unroll
            for (int j = 0; j < 8; ++j) b[j] = Bs[kk][tx * 8 + j];
#pragma unroll
            for (int i = 0; i < 8; ++i)
#pragma unroll
                for (int j = 0; j < 8; ++j) acc[i][j] += a[i] * b[j];
        }
        __syncthreads();
    }

#pragma unroll
    for (int i = 0; i < 8; ++i) {
        int row = bm + ty * 8 + i;
#pragma unroll
        for (int j = 0; j < 8; ++j) {
            int col = bn + tx * 8 + j;
            float v = acc[i][j] + bias[col];
            if (act == 1) v = gelu_tanh(v);
            C[(size_t)row * N + col] = v;
        }
    }
}

// ---------------------------------------------------------------------------
// Blocked sparse attention. One workgroup per (b, h, n); 256 threads.
// Thread t: query row i = t/16, key col / dim-group c = t%16.
// Flash-style online softmax over 16-key tiles.
// Edge blocks (n==0, n==NB-1) attend over ALL 256 key tiles.
// Output written in (B, S, H*DH) token-major layout.
// ---------------------------------------------------------------------------
__global__ __launch_bounds__(256) void attn_kernel(
    const float* __restrict__ qkv, const int* __restrict__ key_idx,
    float* __restrict__ outp)
{
    int bi = blockIdx.x;
    int n = bi % NB_;
    int h = (bi / NB_) % H_;
    int b = bi / (NB_ * H_);

    __shared__ float qs[16][65];
    __shared__ float ks[16][65];
    __shared__ float vs[16][65];

    int t = threadIdx.x;
    int lane = t & 63;
    int i = t >> 4;   // query row
    int c = t & 15;   // key index within tile / output dim group

    // load Q tile (16 x 64)
    {
        int idx = t * 4;
        int qi = idx >> 6, qd = idx & 63;
        const float* src = qkv + ((size_t)(b * S_ + n * BS_ + qi)) * (3 * D_) + h * DH_ + qd;
#pragma unroll
        for (int u = 0; u < 4; ++u) qs[qi][qd + u] = src[u];
    }

    float acc[4] = {0.f, 0.f, 0.f, 0.f};
    float m_old = -1e30f, l = 0.f;

    bool edge = (n == 0) || (n == NB_ - 1);
    int nkb = edge ? NB_ : 7;

    for (int jj = 0; jj < nkb; ++jj) {
        int kb = edge ? jj : key_idx[n * 7 + jj];
        __syncthreads();
        // load K,V tiles (16 x 64 each)
        {
            int idx = t * 4;
            int ri = idx >> 6, rd = idx & 63;
            const float* kp = qkv + ((size_t)(b * S_ + kb * BS_ + ri)) * (3 * D_) + D_ + h * DH_ + rd;
            const float* vp = kp + D_;
#pragma unroll
            for (int u = 0; u < 4; ++u) { ks[ri][rd + u] = kp[u]; vs[ri][rd + u] = vp[u]; }
        }
        __syncthreads();

        // score s(i, c) = <q_i, k_c> * scale
        float s = 0.f;
#pragma unroll
        for (int d = 0; d < 64; ++d) s += qs[i][d] * ks[c][d];
        s *= SCALE_F;

        // online softmax within each 16-lane row group
        float rm = s;
#pragma unroll
        for (int off = 8; off; off >>= 1) rm = fmaxf(rm, __shfl_xor(rm, off, 64));
        float m_new = fmaxf(m_old, rm);
        float p = __expf(s - m_new);
        float rs = p;
#pragma unroll
        for (int off = 8; off; off >>= 1) rs += __shfl_xor(rs, off, 64);
        float corr = __expf(m_old - m_new);
        l = l * corr + rs;
#pragma unroll
        for (int u = 0; u < 4; ++u) acc[u] *= corr;

        int base = lane & 48;
#pragma unroll
        for (int j = 0; j < 16; ++j) {
            float pj = __shfl(p, base + j, 64);
#pragma unroll
            for (int u = 0; u < 4; ++u) acc[u] += pj * vs[j][c * 4 + u];
        }
        m_old = m_new;
    }

    float inv = 1.f / l;
    float* dst = outp + ((size_t)(b * S_ + n * BS_ + i)) * D_ + h * DH_ + c * 4;
#pragma unroll
    for (int u = 0; u < 4; ++u) dst[u] = acc[u] * inv;
}

// ---------------------------------------------------------------------------
// x = LayerNorm(x + g) * gamma + beta   (row-wise, eps=1e-12)
// One block per row; 256 threads, 3 elements each.
// ---------------------------------------------------------------------------
__global__ __launch_bounds__(256) void add_ln_kernel(
    float* __restrict__ x, const float* __restrict__ g,
    const float* __restrict__ gamma, const float* __restrict__ beta)
{
    int row = blockIdx.x;
    int t = threadIdx.x;
    float* xr = x + (size_t)row * D_;
    const float* gr = g + (size_t)row * D_;

    float v[3];
    float s = 0.f, s2 = 0.f;
#pragma unroll
    for (int r = 0; r < 3; ++r) {
        int d = t + 256 * r;
        v[r] = xr[d] + gr[d];
        s += v[r];
        s2 += v[r] * v[r];
    }
#pragma unroll
    for (int off = 32; off; off >>= 1) {
        s  += __shfl_xor(s, off, 64);
        s2 += __shfl_xor(s2, off, 64);
    }
    __shared__ float sA[4], sB[4];
    int wave = t >> 6, lane = t & 63;
    if (lane == 0) { sA[wave] = s; sB[wave] = s2; }
    __syncthreads();
    s  = sA[0] + sA[1] + sA[2] + sA[3];
    s2 = sB[0] + sB[1] + sB[2] + sB[3];
    float mean = s * (1.0f / D_);
    float var = s2 * (1.0f / D_) - mean * mean;
    float rstd = rsqrtf(var + 1e-12f);
#pragma unroll
    for (int r = 0; r < 3; ++r) {
        int d = t + 256 * r;
        xr[d] = (v[r] - mean) * rstd * gamma[d] + beta[d];
    }
}

// ---------------------------------------------------------------------------
// start/end logits: one wave per token row
// ---------------------------------------------------------------------------
__global__ __launch_bounds__(64) void head_logits(
    const float* __restrict__ x, const float* __restrict__ sw,
    const float* __restrict__ ew, float* __restrict__ sl, float* __restrict__ el)
{
    int row = blockIdx.x;
    int lane = threadIdx.x;
    const float* xr = x + (size_t)row * D_;
    float a = 0.f, e = 0.f;
    for (int d = lane; d < D_; d += 64) {
        float xv = xr[d];
        a += xv * sw[d];
        e += xv * ew[d];
    }
#pragma unroll
    for (int off = 32; off; off >>= 1) {
        a += __shfl_xor(a, off, 64);
        e += __shfl_xor(e, off, 64);
    }
    if (lane == 0) { sl[row] = a; el[row] = e; }
}

// ---------------------------------------------------------------------------
// Softmax over S per (output, batch). 4 rows: {start b0, start b1, end b0, end b1}
// ---------------------------------------------------------------------------
__global__ __launch_bounds__(256) void softmax_rows(
    const float* __restrict__ sl, const float* __restrict__ el,
    float* __restrict__ outp)
{
    int r = blockIdx.x;
    const float* src = (r < 2 ? sl : el) + (size_t)(r & 1) * S_;
    float* dst = outp + (r < 2 ? 0 : BT_) + (size_t)(r & 1) * S_;
    int t = threadIdx.x;
    int wave = t >> 6, lane = t & 63;
    __shared__ float sm[4], ss[4];

    float m = -1e30f;
    for (int k = t; k < S_; k += 256) m = fmaxf(m, src[k]);
#pragma unroll
    for (int off = 32; off; off >>= 1) m = fmaxf(m, __shfl_xor(m, off, 64));
    if (lane == 0) sm[wave] = m;
    __syncthreads();
    m = fmaxf(fmaxf(sm[0], sm[1]), fmaxf(sm[2], sm[3]));

    float s = 0.f;
    for (int k = t; k < S_; k += 256) s += __expf(src[k] - m);
#pragma unroll
    for (int off = 32; off; off >>= 1) s += __shfl_xor(s, off, 64);
    if (lane == 0) ss[wave] = s;
    __syncthreads();
    s = ss[0] + ss[1] + ss[2] + ss[3];

    float inv = 1.f / s;
    for (int k = t; k < S_; k += 256) dst[k] = __expf(src[k] - m) * inv;
}

// ---------------------------------------------------------------------------
// pool/discriminator head (tiny): pool0 = tanh(x[0,0]@Wp + bp);
// d = (pool0@d1_W + d1_b)@d2_W + d2_b; disc = softmax(d)
// ---------------------------------------------------------------------------
__global__ __launch_bounds__(256) void disc_kernel(
    const float* __restrict__ x, const float* __restrict__ Wp,
    const float* __restrict__ bp, const float* __restrict__ d1W,
    const float* __restrict__ d1b, const float* __restrict__ d2W,
    const float* __restrict__ d2b, float* __restrict__ out2)
{
    __shared__ float pool[D_];
    __shared__ float h1[20];
    int t = threadIdx.x;
    const float* x0 = x;  // row (b=0, s=0)
    for (int j = t; j < D_; j += 256) {
        float s = bp[j];
        for (int k = 0; k < D_; ++k) s += x0[k] * Wp[(size_t)k * D_ + j];
        pool[j] = tanhf(s);
    }
    __syncthreads();
    if (t < 20) {
        float s = d1b[t];
        for (int k = 0; k < D_; ++k) s += pool[k] * d1W[k * 20 + t];
        h1[t] = s;
    }
    __syncthreads();
    if (t == 0) {
        float d0 = d2b[0], d1v = d2b[1];
#pragma unroll
        for (int u = 0; u < 20; ++u) {
            d0  += h1[u] * d2W[u * 2 + 0];
            d1v += h1[u] * d2W[u * 2 + 1];
        }
        float m = fmaxf(d0, d1v);
        float e0 = __expf(d0 - m), e1 = __expf(d1v - m);
        float inv = 1.f / (e0 + e1);
        out2[0] = e0 * inv;
        out2[1] = e1 * inv;
    }
}

// ---------------------------------------------------------------------------
extern "C" void kernel_launch(void* const* d_in, const int* in_sizes, int n_in,
                              void* d_out, int out_size, void* d_ws, size_t ws_size,
                              hipStream_t stream)
{
    const int*   ids   = (const int*)d_in[0];
    const int*   kbi   = (const int*)d_in[1];
    const float* emb   = (const float*)d_in[2];
    const float* Wqkv  = (const float*)d_in[3];
    const float* bqkv  = (const float*)d_in[4];
    const float* Wo    = (const float*)d_in[5];
    const float* bo    = (const float*)d_in[6];
    const float* ln1g  = (const float*)d_in[7];
    const float* ln1b  = (const float*)d_in[8];
    const float* Wff1  = (const float*)d_in[9];
    const float* bff1  = (const float*)d_in[10];
    const float* Wff2  = (const float*)d_in[11];
    const float* bff2  = (const float*)d_in[12];
    const float* ln2g  = (const float*)d_in[13];
    const float* ln2b  = (const float*)d_in[14];
    const float* Wp    = (const float*)d_in[15];
    const float* bp    = (const float*)d_in[16];
    const float* sw    = (const float*)d_in[17];
    const float* ew    = (const float*)d_in[18];
    const float* d1W   = (const float*)d_in[19];
    const float* d1b   = (const float*)d_in[20];
    const float* d2W   = (const float*)d_in[21];
    const float* d2b   = (const float*)d_in[22];
    float* outp = (float*)d_out;

    float* ws   = (float*)d_ws;
    float* x    = ws;                                  // BT_ * D_
    float* buf1 = x    + (size_t)BT_ * D_;             // BT_ * FF_ (qkv / h / proj-out)
    float* buf2 = buf1 + (size_t)BT_ * FF_;            // BT_ * D_  (attn out / ff2 out)
    float* sl   = buf2 + (size_t)BT_ * D_;             // BT_
    float* el   = sl   + BT_;                          // BT_

    embed_kernel<<<BT_, 256, 0, stream>>>(ids, emb, x);

    for (int l = 0; l < 2; ++l) {
        // qkv = x @ Wqkv[l] + bqkv[l]          (8192 x 2304, K=768)
        gemm_f32<<<dim3((3 * D_) / TBN, BT_ / TBM), 256, 0, stream>>>(
            x, Wqkv + (size_t)l * D_ * 3 * D_, bqkv + (size_t)l * 3 * D_, buf1,
            BT_, 3 * D_, D_, 0);
        // sparse attention -> buf2 (token-major B,S,D)
        attn_kernel<<<B_ * H_ * NB_, 256, 0, stream>>>(buf1, kbi, buf2);
        // g = a @ Wo[l] + bo[l] -> buf1 (qkv dead)
        gemm_f32<<<dim3(D_ / TBN, BT_ / TBM), 256, 0, stream>>>(
            buf2, Wo + (size_t)l * D_ * D_, bo + (size_t)l * D_, buf1,
            BT_, D_, D_, 0);
        // x = LN(x + g)
        add_ln_kernel<<<BT_, 256, 0, stream>>>(x, buf1, ln1g + (size_t)l * D_, ln1b + (size_t)l * D_);
        // h = gelu(x @ Wff1[l] + bff1[l]) -> buf1
        gemm_f32<<<dim3(FF_ / TBN, BT_ / TBM), 256, 0, stream>>>(
            x, Wff1 + (size_t)l * D_ * FF_, bff1 + (size_t)l * FF_, buf1,
            BT_, FF_, D_, 1);
        // g2 = h @ Wff2[l] + bff2[l] -> buf2 (attn out dead)
        gemm_f32<<<dim3(D_ / TBN, BT_ / TBM), 256, 0, stream>>>(
            buf1, Wff2 + (size_t)l * FF_ * D_, bff2 + (size_t)l * D_, buf2,
            BT_, D_, FF_, 0);
        // x = LN(x + g2)
        add_ln_kernel<<<BT_, 256, 0, stream>>>(x, buf2, ln2g + (size_t)l * D_, ln2b + (size_t)l * D_);
    }

    head_logits<<<BT_, 64, 0, stream>>>(x, sw, ew, sl, el);
    softmax_rows<<<4, 256, 0, stream>>>(sl, el, outp);
    disc_kernel<<<1, 256, 0, stream>>>(x, Wp, bp, d1W, d1b, d2W, d2b, outp + 2 * BT_);
}

// Round 2
// 6818.623 us; speedup vs baseline: 1.5394x; 1.5394x over previous
//
#include <hip/hip_runtime.h>
#include <hip/hip_bf16.h>
#include <math.h>

#define B_   2
#define S_   4096
#define D_   768
#define H_   12
#define DH_  64
#define BS_  16
#define NB_  256
#define FF_  3072
#define BT_  (B_ * S_)          // 8192 token rows
#define SCALE_F 0.125f          // 1/sqrt(64)

#define NSPLIT 32               // key-dimension splits for edge attention
#define TILES_PER_SPLIT (NB_ / NSPLIT)   // 8 tiles of 16 keys = 128 keys/split
#define NEDGE (B_ * H_ * 2)              // 48 edge (b,h,e) groups

// ---------------------------------------------------------------------------
// Embedding gather: x[row][d] = embed[ids[row]][d]
// ---------------------------------------------------------------------------
__global__ __launch_bounds__(256) void embed_kernel(
    const int* __restrict__ ids, const float* __restrict__ emb,
    float* __restrict__ x)
{
    int row = blockIdx.x;
    int id = ids[row];
    const float* src = emb + (size_t)id * D_;
    float* dst = x + (size_t)row * D_;
    for (int d = threadIdx.x; d < D_; d += 256) dst[d] = src[d];
}

// ---------------------------------------------------------------------------
// Tiled fp32 GEMM: C[M,N] = A[M,K] @ W[K,N] + bias[N]   (act: 0=none, 1=gelu)
// ---------------------------------------------------------------------------
#define TBM 128
#define TBN 128
#define TBK 16

__device__ __forceinline__ float gelu_tanh(float v)
{
    float v3 = v * v * v;
    return 0.5f * v * (1.0f + tanhf(0.79788456080286535588f * (v + 0.044715f * v3)));
}

__global__ __launch_bounds__(256) void gemm_f32(
    const float* __restrict__ A, const float* __restrict__ W,
    const float* __restrict__ bias, float* __restrict__ C,
    int M, int N, int K, int act)
{
    __shared__ float As[TBK][TBM + 1];
    __shared__ float Bs[TBK][TBN + 1];

    int bm = blockIdx.y * TBM;
    int bn = blockIdx.x * TBN;
    int t  = threadIdx.x;
    int tx = t & 15;       // 0..15
    int ty = t >> 4;       // 0..15

    float acc[8][8];
#pragma unroll
    for (int i = 0; i < 8; ++i)
#pragma unroll
        for (int j = 0; j < 8; ++j) acc[i][j] = 0.f;

    for (int k0 = 0; k0 < K; k0 += TBK) {
#pragma unroll
        for (int r = 0; r < 8; ++r) {
            int m = (t >> 4) + 16 * r;
            int k = t & 15;
            As[k][m] = A[(size_t)(bm + m) * K + k0 + k];
        }
#pragma unroll
        for (int r = 0; r < 8; ++r) {
            int k = (t >> 7) + 2 * r;
            int n = t & 127;
            Bs[k][n] = W[(size_t)(k0 + k) * N + bn + n];
        }
        __syncthreads();
#pragma unroll
        for (int kk = 0; kk < TBK; ++kk) {
            float a[8], b[8];
#pragma unroll
            for (int i = 0; i < 8; ++i) a[i] = As[kk][ty * 8 + i];
#pragma unroll
            for (int j = 0; j < 8; ++j) b[j] = Bs[kk][tx * 8 + j];
#pragma unroll
            for (int i = 0; i < 8; ++i)
#pragma unroll
                for (int j = 0; j < 8; ++j) acc[i][j] += a[i] * b[j];
        }
        __syncthreads();
    }

#pragma unroll
    for (int i = 0; i < 8; ++i) {
        int row = bm + ty * 8 + i;
#pragma unroll
        for (int j = 0; j < 8; ++j) {
            int col = bn + tx * 8 + j;
            float v = acc[i][j] + bias[col];
            if (act == 1) v = gelu_tanh(v);
            C[(size_t)row * N + col] = v;
        }
    }
}

// ---------------------------------------------------------------------------
// Blocked sparse attention, NON-EDGE blocks only (n = 1..NB-2).
// One workgroup per (b, h, n); 256 threads. Thread t: query row i = t/16,
// key col / dim-group c = t%16. Flash-style online softmax over 16-key tiles.
// ---------------------------------------------------------------------------
__global__ __launch_bounds__(256) void attn_sparse(
    const float* __restrict__ qkv, const int* __restrict__ key_idx,
    float* __restrict__ outp)
{
    int bi = blockIdx.x;
    int n = bi % NB_;
    if (n == 0 || n == NB_ - 1) return;   // uniform early exit, no barrier yet
    int h = (bi / NB_) % H_;
    int b = bi / (NB_ * H_);

    __shared__ float qs[16][65];
    __shared__ float ks[16][65];
    __shared__ float vs[16][65];

    int t = threadIdx.x;
    int lane = t & 63;
    int i = t >> 4;   // query row
    int c = t & 15;   // key index within tile / output dim group

    {
        int idx = t * 4;
        int qi = idx >> 6, qd = idx & 63;
        const float* src = qkv + ((size_t)(b * S_ + n * BS_ + qi)) * (3 * D_) + h * DH_ + qd;
#pragma unroll
        for (int u = 0; u < 4; ++u) qs[qi][qd + u] = src[u];
    }

    float acc[4] = {0.f, 0.f, 0.f, 0.f};
    float m_old = -1e30f, l = 0.f;

    for (int jj = 0; jj < 7; ++jj) {
        int kb = key_idx[n * 7 + jj];
        __syncthreads();
        {
            int idx = t * 4;
            int ri = idx >> 6, rd = idx & 63;
            const float* kp = qkv + ((size_t)(b * S_ + kb * BS_ + ri)) * (3 * D_) + D_ + h * DH_ + rd;
            const float* vp = kp + D_;
#pragma unroll
            for (int u = 0; u < 4; ++u) { ks[ri][rd + u] = kp[u]; vs[ri][rd + u] = vp[u]; }
        }
        __syncthreads();

        float s = 0.f;
#pragma unroll
        for (int d = 0; d < 64; ++d) s += qs[i][d] * ks[c][d];
        s *= SCALE_F;

        float rm = s;
#pragma unroll
        for (int off = 8; off; off >>= 1) rm = fmaxf(rm, __shfl_xor(rm, off, 64));
        float m_new = fmaxf(m_old, rm);
        float p = __expf(s - m_new);
        float rs = p;
#pragma unroll
        for (int off = 8; off; off >>= 1) rs += __shfl_xor(rs, off, 64);
        float corr = __expf(m_old - m_new);
        l = l * corr + rs;
#pragma unroll
        for (int u = 0; u < 4; ++u) acc[u] *= corr;

        int base = lane & 48;
#pragma unroll
        for (int j = 0; j < 16; ++j) {
            float pj = __shfl(p, base + j, 64);
#pragma unroll
            for (int u = 0; u < 4; ++u) acc[u] += pj * vs[j][c * 4 + u];
        }
        m_old = m_new;
    }

    float inv = 1.f / l;
    float* dst = outp + ((size_t)(b * S_ + n * BS_ + i)) * D_ + h * DH_ + c * 4;
#pragma unroll
    for (int u = 0; u < 4; ++u) dst[u] = acc[u] * inv;
}

// ---------------------------------------------------------------------------
// Edge attention, split-K partials. Grid: NEDGE * NSPLIT blocks.
// be = ((b*H)+h)*2 + e ; e=0 -> query block 0, e=1 -> query block NB-1.
// Each block processes TILES_PER_SPLIT consecutive 16-key tiles.
// Writes pm[be][split][16], pl[be][split][16], pacc[be][split][16][64].
// ---------------------------------------------------------------------------
__global__ __launch_bounds__(256) void attn_edge_partial(
    const float* __restrict__ qkv, float* __restrict__ pm,
    float* __restrict__ pl, float* __restrict__ pacc)
{
    int gb = blockIdx.x;
    int split = gb % NSPLIT;
    int be = gb / NSPLIT;
    int e = be & 1;
    int h = (be >> 1) % H_;
    int b = be / (2 * H_);
    int n = e ? (NB_ - 1) : 0;

    __shared__ float qs[16][65];
    __shared__ float ks[16][65];
    __shared__ float vs[16][65];

    int t = threadIdx.x;
    int lane = t & 63;
    int i = t >> 4;
    int c = t & 15;

    {
        int idx = t * 4;
        int qi = idx >> 6, qd = idx & 63;
        const float* src = qkv + ((size_t)(b * S_ + n * BS_ + qi)) * (3 * D_) + h * DH_ + qd;
#pragma unroll
        for (int u = 0; u < 4; ++u) qs[qi][qd + u] = src[u];
    }

    float acc[4] = {0.f, 0.f, 0.f, 0.f};
    float m_old = -1e30f, l = 0.f;

    for (int jj = 0; jj < TILES_PER_SPLIT; ++jj) {
        int kb = split * TILES_PER_SPLIT + jj;
        __syncthreads();
        {
            int idx = t * 4;
            int ri = idx >> 6, rd = idx & 63;
            const float* kp = qkv + ((size_t)(b * S_ + kb * BS_ + ri)) * (3 * D_) + D_ + h * DH_ + rd;
            const float* vp = kp + D_;
#pragma unroll
            for (int u = 0; u < 4; ++u) { ks[ri][rd + u] = kp[u]; vs[ri][rd + u] = vp[u]; }
        }
        __syncthreads();

        float s = 0.f;
#pragma unroll
        for (int d = 0; d < 64; ++d) s += qs[i][d] * ks[c][d];
        s *= SCALE_F;

        float rm = s;
#pragma unroll
        for (int off = 8; off; off >>= 1) rm = fmaxf(rm, __shfl_xor(rm, off, 64));
        float m_new = fmaxf(m_old, rm);
        float p = __expf(s - m_new);
        float rs = p;
#pragma unroll
        for (int off = 8; off; off >>= 1) rs += __shfl_xor(rs, off, 64);
        float corr = __expf(m_old - m_new);
        l = l * corr + rs;
#pragma unroll
        for (int u = 0; u < 4; ++u) acc[u] *= corr;

        int base = lane & 48;
#pragma unroll
        for (int j = 0; j < 16; ++j) {
            float pj = __shfl(p, base + j, 64);
#pragma unroll
            for (int u = 0; u < 4; ++u) acc[u] += pj * vs[j][c * 4 + u];
        }
        m_old = m_new;
    }

    int ps = (be * NSPLIT + split) * 16 + i;
    if (c == 0) { pm[ps] = m_old; pl[ps] = l; }
#pragma unroll
    for (int u = 0; u < 4; ++u) pacc[(size_t)ps * 64 + c * 4 + u] = acc[u];
}

// ---------------------------------------------------------------------------
// Edge attention combine: one block per be group; merge NSPLIT partials.
// ---------------------------------------------------------------------------
__global__ __launch_bounds__(256) void attn_edge_combine(
    const float* __restrict__ pm, const float* __restrict__ pl,
    const float* __restrict__ pacc, float* __restrict__ outp)
{
    int be = blockIdx.x;
    int e = be & 1;
    int h = (be >> 1) % H_;
    int b = be / (2 * H_);
    int n = e ? (NB_ - 1) : 0;

    int t = threadIdx.x;
    int i = t >> 4;
    int c = t & 15;

    float M = -1e30f;
#pragma unroll 4
    for (int s = 0; s < NSPLIT; ++s)
        M = fmaxf(M, pm[(be * NSPLIT + s) * 16 + i]);

    float L = 0.f;
    float acc[4] = {0.f, 0.f, 0.f, 0.f};
    for (int s = 0; s < NSPLIT; ++s) {
        int ps = (be * NSPLIT + s) * 16 + i;
        float w = __expf(pm[ps] - M);
        L += pl[ps] * w;
#pragma unroll
        for (int u = 0; u < 4; ++u) acc[u] += pacc[(size_t)ps * 64 + c * 4 + u] * w;
    }

    float inv = 1.f / L;
    float* dst = outp + ((size_t)(b * S_ + n * BS_ + i)) * D_ + h * DH_ + c * 4;
#pragma unroll
    for (int u = 0; u < 4; ++u) dst[u] = acc[u] * inv;
}

// ---------------------------------------------------------------------------
// x = LayerNorm(x + g) * gamma + beta   (row-wise, eps=1e-12)
// ---------------------------------------------------------------------------
__global__ __launch_bounds__(256) void add_ln_kernel(
    float* __restrict__ x, const float* __restrict__ g,
    const float* __restrict__ gamma, const float* __restrict__ beta)
{
    int row = blockIdx.x;
    int t = threadIdx.x;
    float* xr = x + (size_t)row * D_;
    const float* gr = g + (size_t)row * D_;

    float v[3];
    float s = 0.f, s2 = 0.f;
#pragma unroll
    for (int r = 0; r < 3; ++r) {
        int d = t + 256 * r;
        v[r] = xr[d] + gr[d];
        s += v[r];
        s2 += v[r] * v[r];
    }
#pragma unroll
    for (int off = 32; off; off >>= 1) {
        s  += __shfl_xor(s, off, 64);
        s2 += __shfl_xor(s2, off, 64);
    }
    __shared__ float sA[4], sB[4];
    int wave = t >> 6, lane = t & 63;
    if (lane == 0) { sA[wave] = s; sB[wave] = s2; }
    __syncthreads();
    s  = sA[0] + sA[1] + sA[2] + sA[3];
    s2 = sB[0] + sB[1] + sB[2] + sB[3];
    float mean = s * (1.0f / D_);
    float var = s2 * (1.0f / D_) - mean * mean;
    float rstd = rsqrtf(var + 1e-12f);
#pragma unroll
    for (int r = 0; r < 3; ++r) {
        int d = t + 256 * r;
        xr[d] = (v[r] - mean) * rstd * gamma[d] + beta[d];
    }
}

// ---------------------------------------------------------------------------
// start/end logits: one wave per token row
// ---------------------------------------------------------------------------
__global__ __launch_bounds__(64) void head_logits(
    const float* __restrict__ x, const float* __restrict__ sw,
    const float* __restrict__ ew, float* __restrict__ sl, float* __restrict__ el)
{
    int row = blockIdx.x;
    int lane = threadIdx.x;
    const float* xr = x + (size_t)row * D_;
    float a = 0.f, e = 0.f;
    for (int d = lane; d < D_; d += 64) {
        float xv = xr[d];
        a += xv * sw[d];
        e += xv * ew[d];
    }
#pragma unroll
    for (int off = 32; off; off >>= 1) {
        a += __shfl_xor(a, off, 64);
        e += __shfl_xor(e, off, 64);
    }
    if (lane == 0) { sl[row] = a; el[row] = e; }
}

// ---------------------------------------------------------------------------
// Softmax over S per (output, batch).
// ---------------------------------------------------------------------------
__global__ __launch_bounds__(256) void softmax_rows(
    const float* __restrict__ sl, const float* __restrict__ el,
    float* __restrict__ outp)
{
    int r = blockIdx.x;
    const float* src = (r < 2 ? sl : el) + (size_t)(r & 1) * S_;
    float* dst = outp + (r < 2 ? 0 : BT_) + (size_t)(r & 1) * S_;
    int t = threadIdx.x;
    int wave = t >> 6, lane = t & 63;
    __shared__ float sm[4], ss[4];

    float m = -1e30f;
    for (int k = t; k < S_; k += 256) m = fmaxf(m, src[k]);
#pragma unroll
    for (int off = 32; off; off >>= 1) m = fmaxf(m, __shfl_xor(m, off, 64));
    if (lane == 0) sm[wave] = m;
    __syncthreads();
    m = fmaxf(fmaxf(sm[0], sm[1]), fmaxf(sm[2], sm[3]));

    float s = 0.f;
    for (int k = t; k < S_; k += 256) s += __expf(src[k] - m);
#pragma unroll
    for (int off = 32; off; off >>= 1) s += __shfl_xor(s, off, 64);
    if (lane == 0) ss[wave] = s;
    __syncthreads();
    s = ss[0] + ss[1] + ss[2] + ss[3];

    float inv = 1.f / s;
    for (int k = t; k < S_; k += 256) dst[k] = __expf(src[k] - m) * inv;
}

// ---------------------------------------------------------------------------
// pool/discriminator head (tiny)
// ---------------------------------------------------------------------------
__global__ __launch_bounds__(256) void disc_kernel(
    const float* __restrict__ x, const float* __restrict__ Wp,
    const float* __restrict__ bp, const float* __restrict__ d1W,
    const float* __restrict__ d1b, const float* __restrict__ d2W,
    const float* __restrict__ d2b, float* __restrict__ out2)
{
    __shared__ float pool[D_];
    __shared__ float h1[20];
    int t = threadIdx.x;
    const float* x0 = x;
    for (int j = t; j < D_; j += 256) {
        float s = bp[j];
        for (int k = 0; k < D_; ++k) s += x0[k] * Wp[(size_t)k * D_ + j];
        pool[j] = tanhf(s);
    }
    __syncthreads();
    if (t < 20) {
        float s = d1b[t];
        for (int k = 0; k < D_; ++k) s += pool[k] * d1W[k * 20 + t];
        h1[t] = s;
    }
    __syncthreads();
    if (t == 0) {
        float d0 = d2b[0], d1v = d2b[1];
#pragma unroll
        for (int u = 0; u < 20; ++u) {
            d0  += h1[u] * d2W[u * 2 + 0];
            d1v += h1[u] * d2W[u * 2 + 1];
        }
        float m = fmaxf(d0, d1v);
        float e0 = __expf(d0 - m), e1 = __expf(d1v - m);
        float inv = 1.f / (e0 + e1);
        out2[0] = e0 * inv;
        out2[1] = e1 * inv;
    }
}

// ---------------------------------------------------------------------------
extern "C" void kernel_launch(void* const* d_in, const int* in_sizes, int n_in,
                              void* d_out, int out_size, void* d_ws, size_t ws_size,
                              hipStream_t stream)
{
    const int*   ids   = (const int*)d_in[0];
    const int*   kbi   = (const int*)d_in[1];
    const float* emb   = (const float*)d_in[2];
    const float* Wqkv  = (const float*)d_in[3];
    const float* bqkv  = (const float*)d_in[4];
    const float* Wo    = (const float*)d_in[5];
    const float* bo    = (const float*)d_in[6];
    const float* ln1g  = (const float*)d_in[7];
    const float* ln1b  = (const float*)d_in[8];
    const float* Wff1  = (const float*)d_in[9];
    const float* bff1  = (const float*)d_in[10];
    const float* Wff2  = (const float*)d_in[11];
    const float* bff2  = (const float*)d_in[12];
    const float* ln2g  = (const float*)d_in[13];
    const float* ln2b  = (const float*)d_in[14];
    const float* Wp    = (const float*)d_in[15];
    const float* bp    = (const float*)d_in[16];
    const float* sw    = (const float*)d_in[17];
    const float* ew    = (const float*)d_in[18];
    const float* d1W   = (const float*)d_in[19];
    const float* d1b   = (const float*)d_in[20];
    const float* d2W   = (const float*)d_in[21];
    const float* d2b   = (const float*)d_in[22];
    float* outp = (float*)d_out;

    float* ws   = (float*)d_ws;
    float* x    = ws;                                  // BT_ * D_
    float* buf1 = x    + (size_t)BT_ * D_;             // BT_ * FF_ (qkv / h / proj-out)
    float* buf2 = buf1 + (size_t)BT_ * FF_;            // BT_ * D_  (attn out / ff2 out)
    float* sl   = buf2 + (size_t)BT_ * D_;             // BT_
    float* el   = sl   + BT_;                          // BT_
    float* pm   = el   + BT_;                          // NEDGE*NSPLIT*16
    float* pl   = pm   + NEDGE * NSPLIT * 16;          // NEDGE*NSPLIT*16
    float* pacc = pl   + NEDGE * NSPLIT * 16;          // NEDGE*NSPLIT*16*64

    embed_kernel<<<BT_, 256, 0, stream>>>(ids, emb, x);

    for (int l = 0; l < 2; ++l) {
        gemm_f32<<<dim3((3 * D_) / TBN, BT_ / TBM), 256, 0, stream>>>(
            x, Wqkv + (size_t)l * D_ * 3 * D_, bqkv + (size_t)l * 3 * D_, buf1,
            BT_, 3 * D_, D_, 0);
        // sparse attention (non-edge) + split-K edge attention -> buf2
        attn_sparse<<<B_ * H_ * NB_, 256, 0, stream>>>(buf1, kbi, buf2);
        attn_edge_partial<<<NEDGE * NSPLIT, 256, 0, stream>>>(buf1, pm, pl, pacc);
        attn_edge_combine<<<NEDGE, 256, 0, stream>>>(pm, pl, pacc, buf2);
        gemm_f32<<<dim3(D_ / TBN, BT_ / TBM), 256, 0, stream>>>(
            buf2, Wo + (size_t)l * D_ * D_, bo + (size_t)l * D_, buf1,
            BT_, D_, D_, 0);
        add_ln_kernel<<<BT_, 256, 0, stream>>>(x, buf1, ln1g + (size_t)l * D_, ln1b + (size_t)l * D_);
        gemm_f32<<<dim3(FF_ / TBN, BT_ / TBM), 256, 0, stream>>>(
            x, Wff1 + (size_t)l * D_ * FF_, bff1 + (size_t)l * FF_, buf1,
            BT_, FF_, D_, 1);
        gemm_f32<<<dim3(D_ / TBN, BT_ / TBM), 256, 0, stream>>>(
            buf1, Wff2 + (size_t)l * FF_ * D_, bff2 + (size_t)l * D_, buf2,
            BT_, D_, FF_, 0);
        add_ln_kernel<<<BT_, 256, 0, stream>>>(x, buf2, ln2g + (size_t)l * D_, ln2b + (size_t)l * D_);
    }

    head_logits<<<BT_, 64, 0, stream>>>(x, sw, ew, sl, el);
    softmax_rows<<<4, 256, 0, stream>>>(sl, el, outp);
    disc_kernel<<<1, 256, 0, stream>>>(x, Wp, bp, d1W, d1b, d2W, d2b, outp + 2 * BT_);
}

// Round 3
// 1213.386 us; speedup vs baseline: 8.6509x; 5.6195x over previous
//
#include <hip/hip_runtime.h>
#include <hip/hip_bf16.h>
#include <math.h>

#define B_   2
#define S_   4096
#define D_   768
#define H_   12
#define DH_  64
#define BS_  16
#define NB_  256
#define FF_  3072
#define BT_  (B_ * S_)          // 8192 token rows
#define SCALE_F 0.125f          // 1/sqrt(64)

#define NSPLIT 32               // key-dimension splits for edge attention
#define TILES_PER_SPLIT (NB_ / NSPLIT)
#define NEDGE (B_ * H_ * 2)     // 48 edge (b,h,e) groups

typedef _Float16 f16x8 __attribute__((ext_vector_type(8)));
typedef float    f32x4 __attribute__((ext_vector_type(4)));

// async global->LDS, 16B per lane; LDS dest is wave-uniform base + lane*16
#define GLD16(gp, lp) __builtin_amdgcn_global_load_lds( \
    (const __attribute__((address_space(1))) void*)(gp), \
    (__attribute__((address_space(3))) void*)(lp), 16, 0, 0)

__device__ __forceinline__ float gelu_tanh(float v)
{
    float v3 = v * v * v;
    return 0.5f * v * (1.0f + tanhf(0.79788456080286535588f * (v + 0.044715f * v3)));
}

// ---------------------------------------------------------------------------
// Weight convert + transpose: W fp32 [K][N] -> Wt f16 [N][K]
// ---------------------------------------------------------------------------
__global__ __launch_bounds__(256) void wconvert_kernel(
    const float* __restrict__ W, _Float16* __restrict__ Wt, int K, int N)
{
    __shared__ float tile[32][33];
    int n0 = blockIdx.x * 32, k0 = blockIdx.y * 32;
    int t = threadIdx.x;
    int r = t >> 5, c = t & 31;
#pragma unroll
    for (int rr = 0; rr < 32; rr += 8)
        tile[r + rr][c] = W[(size_t)(k0 + r + rr) * N + n0 + c];
    __syncthreads();
#pragma unroll
    for (int rr = 0; rr < 32; rr += 8)
        Wt[(size_t)(n0 + r + rr) * K + k0 + c] = (_Float16)tile[c][r + rr];
}

// ---------------------------------------------------------------------------
// Embedding gather -> x fp32 and xb f16
// ---------------------------------------------------------------------------
__global__ __launch_bounds__(256) void embed_kernel(
    const int* __restrict__ ids, const float* __restrict__ emb,
    float* __restrict__ x, _Float16* __restrict__ xb)
{
    int row = blockIdx.x;
    int id = ids[row];
    const float* src = emb + (size_t)id * D_;
    float* dst = x + (size_t)row * D_;
    _Float16* dst16 = xb + (size_t)row * D_;
    for (int d = threadIdx.x; d < D_; d += 256) {
        float v = src[d];
        dst[d] = v;
        dst16[d] = (_Float16)v;
    }
}

// ---------------------------------------------------------------------------
// MFMA fp16 GEMM: C[M,N] = A[M,K] @ Wt[N,K]^T + bias
// 128x128 tile, BK=32, 4 waves, 4x4 16x16x32 frags/wave.
// LDS staged via global_load_lds(16B) with XOR-swizzled source; reads apply
// the same involution: chunk' = chunk ^ ((row>>1)&3)  (chunks are 16B).
// ---------------------------------------------------------------------------
template<int ACT, int OUT16>
__global__ __launch_bounds__(256) void gemm_f16(
    const _Float16* __restrict__ A, const _Float16* __restrict__ Wt,
    const float* __restrict__ bias, void* __restrict__ Cp,
    int M, int N, int K)
{
    __shared__ __attribute__((aligned(16))) _Float16 As[128 * 32];
    __shared__ __attribute__((aligned(16))) _Float16 Bs[128 * 32];

    int t = threadIdx.x;
    int w = t >> 6, l = t & 63;
    int bm = blockIdx.y * 128, bn = blockIdx.x * 128;
    int wr = (w >> 1) * 64, wc = (w & 1) * 64;

    f32x4 acc[4][4];
#pragma unroll
    for (int i = 0; i < 4; ++i)
#pragma unroll
        for (int j = 0; j < 4; ++j) acc[i][j] = (f32x4){0.f, 0.f, 0.f, 0.f};

    // staging: wave w owns chunks {2w, 2w+1} of each tile; chunk = 16 rows,
    // lane l covers row ch*16 + l/4, 16B-group l%4 (LDS position), loading
    // global 16B-group (l%4) ^ ((row>>1)&3).
    int ch0 = w * 2, ch1 = w * 2 + 1;
    int row0 = ch0 * 16 + (l >> 2), row1 = ch1 * 16 + (l >> 2);
    int cs0 = (l & 3) ^ ((row0 >> 1) & 3);
    int cs1 = (l & 3) ^ ((row1 >> 1) & 3);
    const _Float16* ga0 = A  + (size_t)(bm + row0) * K + cs0 * 8;
    const _Float16* ga1 = A  + (size_t)(bm + row1) * K + cs1 * 8;
    const _Float16* gb0 = Wt + (size_t)(bn + row0) * K + cs0 * 8;
    const _Float16* gb1 = Wt + (size_t)(bn + row1) * K + cs1 * 8;
    _Float16* lA0 = As + ch0 * 512;   // 512 f16 = 1024B per chunk
    _Float16* lA1 = As + ch1 * 512;
    _Float16* lB0 = Bs + ch0 * 512;
    _Float16* lB1 = Bs + ch1 * 512;

    // fragment LDS offsets (f16 elements), swizzled
    int aoff[4], boff[4];
#pragma unroll
    for (int i = 0; i < 4; ++i) {
        int ar = wr + i * 16 + (l & 15);
        aoff[i] = ar * 32 + ((((l >> 4)) ^ ((ar >> 1) & 3)) << 3);
        int br = wc + i * 16 + (l & 15);
        boff[i] = br * 32 + ((((l >> 4)) ^ ((br >> 1) & 3)) << 3);
    }

    for (int k0 = 0; k0 < K; k0 += 32) {
        GLD16(ga0 + k0, lA0);
        GLD16(ga1 + k0, lA1);
        GLD16(gb0 + k0, lB0);
        GLD16(gb1 + k0, lB1);
        __syncthreads();   // drains vmcnt (LDS writes) + lgkm

        f16x8 af[4], bf[4];
#pragma unroll
        for (int i = 0; i < 4; ++i) {
            af[i] = *(const f16x8*)(As + aoff[i]);
            bf[i] = *(const f16x8*)(Bs + boff[i]);
        }
#pragma unroll
        for (int i = 0; i < 4; ++i)
#pragma unroll
            for (int j = 0; j < 4; ++j)
                acc[i][j] = __builtin_amdgcn_mfma_f32_16x16x32_f16(
                    af[i], bf[j], acc[i][j], 0, 0, 0);
        __syncthreads();   // protect LDS before next stage
    }

    // epilogue: C/D layout col = lane&15, row = (lane>>4)*4 + reg
#pragma unroll
    for (int i = 0; i < 4; ++i) {
        int rowb = bm + wr + i * 16 + ((l >> 4) << 2);
#pragma unroll
        for (int j = 0; j < 4; ++j) {
            int col = bn + wc + j * 16 + (l & 15);
            float bv = bias[col];
#pragma unroll
            for (int r = 0; r < 4; ++r) {
                float v = acc[i][j][r] + bv;
                if (ACT) v = gelu_tanh(v);
                if (OUT16)
                    ((_Float16*)Cp)[(size_t)(rowb + r) * N + col] = (_Float16)v;
                else
                    ((float*)Cp)[(size_t)(rowb + r) * N + col] = v;
            }
        }
    }
}

// ---------------------------------------------------------------------------
// Blocked sparse attention, non-edge blocks (qkv in f16, out f16)
// ---------------------------------------------------------------------------
__global__ __launch_bounds__(256) void attn_sparse(
    const _Float16* __restrict__ qkv, const int* __restrict__ key_idx,
    _Float16* __restrict__ outp)
{
    int bi = blockIdx.x;
    int n = bi % NB_;
    if (n == 0 || n == NB_ - 1) return;
    int h = (bi / NB_) % H_;
    int b = bi / (NB_ * H_);

    __shared__ float qs[16][65];
    __shared__ float ks[16][65];
    __shared__ float vs[16][65];

    int t = threadIdx.x;
    int lane = t & 63;
    int i = t >> 4;
    int c = t & 15;

    {
        int idx = t * 4;
        int qi = idx >> 6, qd = idx & 63;
        const _Float16* src = qkv + ((size_t)(b * S_ + n * BS_ + qi)) * (3 * D_) + h * DH_ + qd;
#pragma unroll
        for (int u = 0; u < 4; ++u) qs[qi][qd + u] = (float)src[u];
    }

    float acc[4] = {0.f, 0.f, 0.f, 0.f};
    float m_old = -1e30f, l = 0.f;

    for (int jj = 0; jj < 7; ++jj) {
        int kb = key_idx[n * 7 + jj];
        __syncthreads();
        {
            int idx = t * 4;
            int ri = idx >> 6, rd = idx & 63;
            const _Float16* kp = qkv + ((size_t)(b * S_ + kb * BS_ + ri)) * (3 * D_) + D_ + h * DH_ + rd;
            const _Float16* vp = kp + D_;
#pragma unroll
            for (int u = 0; u < 4; ++u) { ks[ri][rd + u] = (float)kp[u]; vs[ri][rd + u] = (float)vp[u]; }
        }
        __syncthreads();

        float s = 0.f;
#pragma unroll
        for (int d = 0; d < 64; ++d) s += qs[i][d] * ks[c][d];
        s *= SCALE_F;

        float rm = s;
#pragma unroll
        for (int off = 8; off; off >>= 1) rm = fmaxf(rm, __shfl_xor(rm, off, 64));
        float m_new = fmaxf(m_old, rm);
        float p = __expf(s - m_new);
        float rs = p;
#pragma unroll
        for (int off = 8; off; off >>= 1) rs += __shfl_xor(rs, off, 64);
        float corr = __expf(m_old - m_new);
        l = l * corr + rs;
#pragma unroll
        for (int u = 0; u < 4; ++u) acc[u] *= corr;

        int base = lane & 48;
#pragma unroll
        for (int j = 0; j < 16; ++j) {
            float pj = __shfl(p, base + j, 64);
#pragma unroll
            for (int u = 0; u < 4; ++u) acc[u] += pj * vs[j][c * 4 + u];
        }
        m_old = m_new;
    }

    float inv = 1.f / l;
    _Float16* dst = outp + ((size_t)(b * S_ + n * BS_ + i)) * D_ + h * DH_ + c * 4;
#pragma unroll
    for (int u = 0; u < 4; ++u) dst[u] = (_Float16)(acc[u] * inv);
}

// ---------------------------------------------------------------------------
// Edge attention split-K partials (qkv f16, partials fp32)
// ---------------------------------------------------------------------------
__global__ __launch_bounds__(256) void attn_edge_partial(
    const _Float16* __restrict__ qkv, float* __restrict__ pm,
    float* __restrict__ pl, float* __restrict__ pacc)
{
    int gb = blockIdx.x;
    int split = gb % NSPLIT;
    int be = gb / NSPLIT;
    int e = be & 1;
    int h = (be >> 1) % H_;
    int b = be / (2 * H_);
    int n = e ? (NB_ - 1) : 0;

    __shared__ float qs[16][65];
    __shared__ float ks[16][65];
    __shared__ float vs[16][65];

    int t = threadIdx.x;
    int lane = t & 63;
    int i = t >> 4;
    int c = t & 15;

    {
        int idx = t * 4;
        int qi = idx >> 6, qd = idx & 63;
        const _Float16* src = qkv + ((size_t)(b * S_ + n * BS_ + qi)) * (3 * D_) + h * DH_ + qd;
#pragma unroll
        for (int u = 0; u < 4; ++u) qs[qi][qd + u] = (float)src[u];
    }

    float acc[4] = {0.f, 0.f, 0.f, 0.f};
    float m_old = -1e30f, l = 0.f;

    for (int jj = 0; jj < TILES_PER_SPLIT; ++jj) {
        int kb = split * TILES_PER_SPLIT + jj;
        __syncthreads();
        {
            int idx = t * 4;
            int ri = idx >> 6, rd = idx & 63;
            const _Float16* kp = qkv + ((size_t)(b * S_ + kb * BS_ + ri)) * (3 * D_) + D_ + h * DH_ + rd;
            const _Float16* vp = kp + D_;
#pragma unroll
            for (int u = 0; u < 4; ++u) { ks[ri][rd + u] = (float)kp[u]; vs[ri][rd + u] = (float)vp[u]; }
        }
        __syncthreads();

        float s = 0.f;
#pragma unroll
        for (int d = 0; d < 64; ++d) s += qs[i][d] * ks[c][d];
        s *= SCALE_F;

        float rm = s;
#pragma unroll
        for (int off = 8; off; off >>= 1) rm = fmaxf(rm, __shfl_xor(rm, off, 64));
        float m_new = fmaxf(m_old, rm);
        float p = __expf(s - m_new);
        float rs = p;
#pragma unroll
        for (int off = 8; off; off >>= 1) rs += __shfl_xor(rs, off, 64);
        float corr = __expf(m_old - m_new);
        l = l * corr + rs;
#pragma unroll
        for (int u = 0; u < 4; ++u) acc[u] *= corr;

        int base = lane & 48;
#pragma unroll
        for (int j = 0; j < 16; ++j) {
            float pj = __shfl(p, base + j, 64);
#pragma unroll
            for (int u = 0; u < 4; ++u) acc[u] += pj * vs[j][c * 4 + u];
        }
        m_old = m_new;
    }

    int ps = (be * NSPLIT + split) * 16 + i;
    if (c == 0) { pm[ps] = m_old; pl[ps] = l; }
#pragma unroll
    for (int u = 0; u < 4; ++u) pacc[(size_t)ps * 64 + c * 4 + u] = acc[u];
}

__global__ __launch_bounds__(256) void attn_edge_combine(
    const float* __restrict__ pm, const float* __restrict__ pl,
    const float* __restrict__ pacc, _Float16* __restrict__ outp)
{
    int be = blockIdx.x;
    int e = be & 1;
    int h = (be >> 1) % H_;
    int b = be / (2 * H_);
    int n = e ? (NB_ - 1) : 0;

    int t = threadIdx.x;
    int i = t >> 4;
    int c = t & 15;

    float M = -1e30f;
#pragma unroll 4
    for (int s = 0; s < NSPLIT; ++s)
        M = fmaxf(M, pm[(be * NSPLIT + s) * 16 + i]);

    float L = 0.f;
    float acc[4] = {0.f, 0.f, 0.f, 0.f};
    for (int s = 0; s < NSPLIT; ++s) {
        int ps = (be * NSPLIT + s) * 16 + i;
        float wgt = __expf(pm[ps] - M);
        L += pl[ps] * wgt;
#pragma unroll
        for (int u = 0; u < 4; ++u) acc[u] += pacc[(size_t)ps * 64 + c * 4 + u] * wgt;
    }

    float inv = 1.f / L;
    _Float16* dst = outp + ((size_t)(b * S_ + n * BS_ + i)) * D_ + h * DH_ + c * 4;
#pragma unroll
    for (int u = 0; u < 4; ++u) dst[u] = (_Float16)(acc[u] * inv);
}

// ---------------------------------------------------------------------------
// x = LayerNorm(x + g); writes fp32 x and f16 xb
// ---------------------------------------------------------------------------
__global__ __launch_bounds__(256) void add_ln_kernel(
    float* __restrict__ x, const float* __restrict__ g,
    const float* __restrict__ gamma, const float* __restrict__ beta,
    _Float16* __restrict__ xb)
{
    int row = blockIdx.x;
    int t = threadIdx.x;
    float* xr = x + (size_t)row * D_;
    const float* gr = g + (size_t)row * D_;
    _Float16* br = xb + (size_t)row * D_;

    float v[3];
    float s = 0.f, s2 = 0.f;
#pragma unroll
    for (int r = 0; r < 3; ++r) {
        int d = t + 256 * r;
        v[r] = xr[d] + gr[d];
        s += v[r];
        s2 += v[r] * v[r];
    }
#pragma unroll
    for (int off = 32; off; off >>= 1) {
        s  += __shfl_xor(s, off, 64);
        s2 += __shfl_xor(s2, off, 64);
    }
    __shared__ float sA[4], sB[4];
    int wave = t >> 6, lane = t & 63;
    if (lane == 0) { sA[wave] = s; sB[wave] = s2; }
    __syncthreads();
    s  = sA[0] + sA[1] + sA[2] + sA[3];
    s2 = sB[0] + sB[1] + sB[2] + sB[3];
    float mean = s * (1.0f / D_);
    float var = s2 * (1.0f / D_) - mean * mean;
    float rstd = rsqrtf(var + 1e-12f);
#pragma unroll
    for (int r = 0; r < 3; ++r) {
        int d = t + 256 * r;
        float o = (v[r] - mean) * rstd * gamma[d] + beta[d];
        xr[d] = o;
        br[d] = (_Float16)o;
    }
}

// ---------------------------------------------------------------------------
__global__ __launch_bounds__(64) void head_logits(
    const float* __restrict__ x, const float* __restrict__ sw,
    const float* __restrict__ ew, float* __restrict__ sl, float* __restrict__ el)
{
    int row = blockIdx.x;
    int lane = threadIdx.x;
    const float* xr = x + (size_t)row * D_;
    float a = 0.f, e = 0.f;
    for (int d = lane; d < D_; d += 64) {
        float xv = xr[d];
        a += xv * sw[d];
        e += xv * ew[d];
    }
#pragma unroll
    for (int off = 32; off; off >>= 1) {
        a += __shfl_xor(a, off, 64);
        e += __shfl_xor(e, off, 64);
    }
    if (lane == 0) { sl[row] = a; el[row] = e; }
}

__global__ __launch_bounds__(256) void softmax_rows(
    const float* __restrict__ sl, const float* __restrict__ el,
    float* __restrict__ outp)
{
    int r = blockIdx.x;
    const float* src = (r < 2 ? sl : el) + (size_t)(r & 1) * S_;
    float* dst = outp + (r < 2 ? 0 : BT_) + (size_t)(r & 1) * S_;
    int t = threadIdx.x;
    int wave = t >> 6, lane = t & 63;
    __shared__ float sm[4], ss[4];

    float m = -1e30f;
    for (int k = t; k < S_; k += 256) m = fmaxf(m, src[k]);
#pragma unroll
    for (int off = 32; off; off >>= 1) m = fmaxf(m, __shfl_xor(m, off, 64));
    if (lane == 0) sm[wave] = m;
    __syncthreads();
    m = fmaxf(fmaxf(sm[0], sm[1]), fmaxf(sm[2], sm[3]));

    float s = 0.f;
    for (int k = t; k < S_; k += 256) s += __expf(src[k] - m);
#pragma unroll
    for (int off = 32; off; off >>= 1) s += __shfl_xor(s, off, 64);
    if (lane == 0) ss[wave] = s;
    __syncthreads();
    s = ss[0] + ss[1] + ss[2] + ss[3];

    float inv = 1.f / s;
    for (int k = t; k < S_; k += 256) dst[k] = __expf(src[k] - m) * inv;
}

__global__ __launch_bounds__(256) void disc_kernel(
    const float* __restrict__ x, const float* __restrict__ Wp,
    const float* __restrict__ bp, const float* __restrict__ d1W,
    const float* __restrict__ d1b, const float* __restrict__ d2W,
    const float* __restrict__ d2b, float* __restrict__ out2)
{
    __shared__ float pool[D_];
    __shared__ float h1[20];
    int t = threadIdx.x;
    const float* x0 = x;
    for (int j = t; j < D_; j += 256) {
        float s = bp[j];
        for (int k = 0; k < D_; ++k) s += x0[k] * Wp[(size_t)k * D_ + j];
        pool[j] = tanhf(s);
    }
    __syncthreads();
    if (t < 20) {
        float s = d1b[t];
        for (int k = 0; k < D_; ++k) s += pool[k] * d1W[k * 20 + t];
        h1[t] = s;
    }
    __syncthreads();
    if (t == 0) {
        float d0 = d2b[0], d1v = d2b[1];
#pragma unroll
        for (int u = 0; u < 20; ++u) {
            d0  += h1[u] * d2W[u * 2 + 0];
            d1v += h1[u] * d2W[u * 2 + 1];
        }
        float m = fmaxf(d0, d1v);
        float e0 = __expf(d0 - m), e1 = __expf(d1v - m);
        float inv = 1.f / (e0 + e1);
        out2[0] = e0 * inv;
        out2[1] = e1 * inv;
    }
}

// ---------------------------------------------------------------------------
extern "C" void kernel_launch(void* const* d_in, const int* in_sizes, int n_in,
                              void* d_out, int out_size, void* d_ws, size_t ws_size,
                              hipStream_t stream)
{
    const int*   ids   = (const int*)d_in[0];
    const int*   kbi   = (const int*)d_in[1];
    const float* emb   = (const float*)d_in[2];
    const float* Wqkv  = (const float*)d_in[3];
    const float* bqkv  = (const float*)d_in[4];
    const float* Wo    = (const float*)d_in[5];
    const float* bo    = (const float*)d_in[6];
    const float* ln1g  = (const float*)d_in[7];
    const float* ln1b  = (const float*)d_in[8];
    const float* Wff1  = (const float*)d_in[9];
    const float* bff1  = (const float*)d_in[10];
    const float* Wff2  = (const float*)d_in[11];
    const float* bff2  = (const float*)d_in[12];
    const float* ln2g  = (const float*)d_in[13];
    const float* ln2b  = (const float*)d_in[14];
    const float* Wp    = (const float*)d_in[15];
    const float* bp    = (const float*)d_in[16];
    const float* sw    = (const float*)d_in[17];
    const float* ew    = (const float*)d_in[18];
    const float* d1W   = (const float*)d_in[19];
    const float* d1b   = (const float*)d_in[20];
    const float* d2W   = (const float*)d_in[21];
    const float* d2b   = (const float*)d_in[22];
    float* outp = (float*)d_out;

    // workspace carve (float units; all region starts 16B-aligned)
    float* ws   = (float*)d_ws;
    float* x    = ws;                          // 6,291,456 f32
    float* xbf  = x   + (size_t)BT_ * D_;      // 3,145,728 (f16 xb)
    float* r1f  = xbf + (size_t)BT_ * D_ / 2;  // 12,582,912 (f16 qkv / f16 h)
    float* abf  = r1f + (size_t)BT_ * FF_ / 2; // 3,145,728 (f16 attn out)
    float* r2   = abf + (size_t)BT_ * D_ / 2;  // 6,291,456 f32 (proj/ff2; partials early)
    float* wtf  = r2  + (size_t)BT_ * D_;      // 7,077,888 (f16 weights)
    float* sl   = wtf + 7077888;
    float* el   = sl  + BT_;

    _Float16* xb    = (_Float16*)xbf;
    _Float16* qkv16 = (_Float16*)r1f;
    _Float16* h16   = (_Float16*)r1f;
    _Float16* ab    = (_Float16*)abf;
    float* pm   = r2;
    float* pl   = r2 + NEDGE * NSPLIT * 16;
    float* pacc = pl + NEDGE * NSPLIT * 16;

    _Float16* Wt    = (_Float16*)wtf;
    _Float16* WqkvT = Wt;                               // 2 x [2304][768]
    _Float16* WoT   = WqkvT + (size_t)2 * 2304 * 768;   // 2 x [768][768]
    _Float16* Wff1T = WoT   + (size_t)2 * 768 * 768;    // 2 x [3072][768]
    _Float16* Wff2T = Wff1T + (size_t)2 * 3072 * 768;   // 2 x [768][3072]

    // weight convert+transpose (8 launches, ~85MB total traffic)
    for (int l = 0; l < 2; ++l) {
        wconvert_kernel<<<dim3(2304/32, 768/32), 256, 0, stream>>>(
            Wqkv + (size_t)l * 768 * 2304, WqkvT + (size_t)l * 2304 * 768, 768, 2304);
        wconvert_kernel<<<dim3(768/32, 768/32), 256, 0, stream>>>(
            Wo + (size_t)l * 768 * 768, WoT + (size_t)l * 768 * 768, 768, 768);
        wconvert_kernel<<<dim3(3072/32, 768/32), 256, 0, stream>>>(
            Wff1 + (size_t)l * 768 * 3072, Wff1T + (size_t)l * 3072 * 768, 768, 3072);
        wconvert_kernel<<<dim3(768/32, 3072/32), 256, 0, stream>>>(
            Wff2 + (size_t)l * 3072 * 768, Wff2T + (size_t)l * 768 * 3072, 3072, 768);
    }

    embed_kernel<<<BT_, 256, 0, stream>>>(ids, emb, x, xb);

    for (int l = 0; l < 2; ++l) {
        // qkv (f16 out): [8192 x 2304], K=768
        gemm_f16<0,1><<<dim3(2304/128, BT_/128), 256, 0, stream>>>(
            xb, WqkvT + (size_t)l * 2304 * 768, bqkv + (size_t)l * 3 * D_,
            qkv16, BT_, 3 * D_, D_);
        attn_sparse<<<B_ * H_ * NB_, 256, 0, stream>>>(qkv16, kbi, ab);
        attn_edge_partial<<<NEDGE * NSPLIT, 256, 0, stream>>>(qkv16, pm, pl, pacc);
        attn_edge_combine<<<NEDGE, 256, 0, stream>>>(pm, pl, pacc, ab);
        // proj (f32 out): [8192 x 768], K=768
        gemm_f16<0,0><<<dim3(768/128, BT_/128), 256, 0, stream>>>(
            ab, WoT + (size_t)l * 768 * 768, bo + (size_t)l * D_,
            r2, BT_, D_, D_);
        add_ln_kernel<<<BT_, 256, 0, stream>>>(x, r2, ln1g + (size_t)l * D_, ln1b + (size_t)l * D_, xb);
        // ff1 + gelu (f16 out): [8192 x 3072], K=768
        gemm_f16<1,1><<<dim3(3072/128, BT_/128), 256, 0, stream>>>(
            xb, Wff1T + (size_t)l * 3072 * 768, bff1 + (size_t)l * FF_,
            h16, BT_, FF_, D_);
        // ff2 (f32 out): [8192 x 768], K=3072
        gemm_f16<0,0><<<dim3(768/128, BT_/128), 256, 0, stream>>>(
            h16, Wff2T + (size_t)l * 768 * 3072, bff2 + (size_t)l * D_,
            r2, BT_, D_, FF_);
        add_ln_kernel<<<BT_, 256, 0, stream>>>(x, r2, ln2g + (size_t)l * D_, ln2b + (size_t)l * D_, xb);
    }

    head_logits<<<BT_, 64, 0, stream>>>(x, sw, ew, sl, el);
    softmax_rows<<<4, 256, 0, stream>>>(sl, el, outp);
    disc_kernel<<<1, 256, 0, stream>>>(x, Wp, bp, d1W, d1b, d2W, d2b, outp + 2 * BT_);
}

// Round 4
// 1089.722 us; speedup vs baseline: 9.6326x; 1.1135x over previous
//
#include <hip/hip_runtime.h>
#include <hip/hip_bf16.h>
#include <math.h>

#define B_   2
#define S_   4096
#define D_   768
#define H_   12
#define DH_  64
#define BS_  16
#define NB_  256
#define FF_  3072
#define BT_  (B_ * S_)          // 8192 token rows
#define SCALE_F 0.125f          // 1/sqrt(64)

#define NSPLIT 32               // key-dimension splits for edge attention
#define TILES_PER_SPLIT (NB_ / NSPLIT)
#define NEDGE (B_ * H_ * 2)     // 48 edge (b,h,e) groups

#define DKS 8                   // disc pool k-splits
#define DKC (D_ / DKS)          // 96 rows per split

typedef _Float16 f16x8 __attribute__((ext_vector_type(8)));
typedef float    f32x4 __attribute__((ext_vector_type(4)));

// async global->LDS, 16B per lane; LDS dest is wave-uniform base + lane*16
#define GLD16(gp, lp) __builtin_amdgcn_global_load_lds( \
    (const __attribute__((address_space(1))) void*)(gp), \
    (__attribute__((address_space(3))) void*)(lp), 16, 0, 0)

__device__ __forceinline__ float gelu_tanh(float v)
{
    float v3 = v * v * v;
    return 0.5f * v * (1.0f + tanhf(0.79788456080286535588f * (v + 0.044715f * v3)));
}

// ---------------------------------------------------------------------------
// Weight convert + transpose: W fp32 [K][N] -> Wt f16 [N][K]
// ---------------------------------------------------------------------------
__global__ __launch_bounds__(256) void wconvert_kernel(
    const float* __restrict__ W, _Float16* __restrict__ Wt, int K, int N)
{
    __shared__ float tile[32][33];
    int n0 = blockIdx.x * 32, k0 = blockIdx.y * 32;
    int t = threadIdx.x;
    int r = t >> 5, c = t & 31;
#pragma unroll
    for (int rr = 0; rr < 32; rr += 8)
        tile[r + rr][c] = W[(size_t)(k0 + r + rr) * N + n0 + c];
    __syncthreads();
#pragma unroll
    for (int rr = 0; rr < 32; rr += 8)
        Wt[(size_t)(n0 + r + rr) * K + k0 + c] = (_Float16)tile[c][r + rr];
}

// ---------------------------------------------------------------------------
// Embedding gather -> x fp32 and xb f16
// ---------------------------------------------------------------------------
__global__ __launch_bounds__(256) void embed_kernel(
    const int* __restrict__ ids, const float* __restrict__ emb,
    float* __restrict__ x, _Float16* __restrict__ xb)
{
    int row = blockIdx.x;
    int id = ids[row];
    const float* src = emb + (size_t)id * D_;
    float* dst = x + (size_t)row * D_;
    _Float16* dst16 = xb + (size_t)row * D_;
    for (int d = threadIdx.x; d < D_; d += 256) {
        float v = src[d];
        dst[d] = v;
        dst16[d] = (_Float16)v;
    }
}

// ---------------------------------------------------------------------------
// MFMA fp16 GEMM: C[M,N] = A[M,K] @ Wt[N,K]^T + bias
// ---------------------------------------------------------------------------
template<int ACT, int OUT16>
__global__ __launch_bounds__(256) void gemm_f16(
    const _Float16* __restrict__ A, const _Float16* __restrict__ Wt,
    const float* __restrict__ bias, void* __restrict__ Cp,
    int M, int N, int K)
{
    __shared__ __attribute__((aligned(16))) _Float16 As[128 * 32];
    __shared__ __attribute__((aligned(16))) _Float16 Bs[128 * 32];

    int t = threadIdx.x;
    int w = t >> 6, l = t & 63;
    int bm = blockIdx.y * 128, bn = blockIdx.x * 128;
    int wr = (w >> 1) * 64, wc = (w & 1) * 64;

    f32x4 acc[4][4];
#pragma unroll
    for (int i = 0; i < 4; ++i)
#pragma unroll
        for (int j = 0; j < 4; ++j) acc[i][j] = (f32x4){0.f, 0.f, 0.f, 0.f};

    int ch0 = w * 2, ch1 = w * 2 + 1;
    int row0 = ch0 * 16 + (l >> 2), row1 = ch1 * 16 + (l >> 2);
    int cs0 = (l & 3) ^ ((row0 >> 1) & 3);
    int cs1 = (l & 3) ^ ((row1 >> 1) & 3);
    const _Float16* ga0 = A  + (size_t)(bm + row0) * K + cs0 * 8;
    const _Float16* ga1 = A  + (size_t)(bm + row1) * K + cs1 * 8;
    const _Float16* gb0 = Wt + (size_t)(bn + row0) * K + cs0 * 8;
    const _Float16* gb1 = Wt + (size_t)(bn + row1) * K + cs1 * 8;
    _Float16* lA0 = As + ch0 * 512;
    _Float16* lA1 = As + ch1 * 512;
    _Float16* lB0 = Bs + ch0 * 512;
    _Float16* lB1 = Bs + ch1 * 512;

    int aoff[4], boff[4];
#pragma unroll
    for (int i = 0; i < 4; ++i) {
        int ar = wr + i * 16 + (l & 15);
        aoff[i] = ar * 32 + ((((l >> 4)) ^ ((ar >> 1) & 3)) << 3);
        int br = wc + i * 16 + (l & 15);
        boff[i] = br * 32 + ((((l >> 4)) ^ ((br >> 1) & 3)) << 3);
    }

    for (int k0 = 0; k0 < K; k0 += 32) {
        GLD16(ga0 + k0, lA0);
        GLD16(ga1 + k0, lA1);
        GLD16(gb0 + k0, lB0);
        GLD16(gb1 + k0, lB1);
        __syncthreads();

        f16x8 af[4], bf[4];
#pragma unroll
        for (int i = 0; i < 4; ++i) {
            af[i] = *(const f16x8*)(As + aoff[i]);
            bf[i] = *(const f16x8*)(Bs + boff[i]);
        }
#pragma unroll
        for (int i = 0; i < 4; ++i)
#pragma unroll
            for (int j = 0; j < 4; ++j)
                acc[i][j] = __builtin_amdgcn_mfma_f32_16x16x32_f16(
                    af[i], bf[j], acc[i][j], 0, 0, 0);
        __syncthreads();
    }

#pragma unroll
    for (int i = 0; i < 4; ++i) {
        int rowb = bm + wr + i * 16 + ((l >> 4) << 2);
#pragma unroll
        for (int j = 0; j < 4; ++j) {
            int col = bn + wc + j * 16 + (l & 15);
            float bv = bias[col];
#pragma unroll
            for (int r = 0; r < 4; ++r) {
                float v = acc[i][j][r] + bv;
                if (ACT) v = gelu_tanh(v);
                if (OUT16)
                    ((_Float16*)Cp)[(size_t)(rowb + r) * N + col] = (_Float16)v;
                else
                    ((float*)Cp)[(size_t)(rowb + r) * N + col] = v;
            }
        }
    }
}

// ---------------------------------------------------------------------------
// Blocked sparse attention, non-edge blocks (qkv in f16, out f16)
// ---------------------------------------------------------------------------
__global__ __launch_bounds__(256) void attn_sparse(
    const _Float16* __restrict__ qkv, const int* __restrict__ key_idx,
    _Float16* __restrict__ outp)
{
    int bi = blockIdx.x;
    int n = bi % NB_;
    if (n == 0 || n == NB_ - 1) return;
    int h = (bi / NB_) % H_;
    int b = bi / (NB_ * H_);

    __shared__ float qs[16][65];
    __shared__ float ks[16][65];
    __shared__ float vs[16][65];

    int t = threadIdx.x;
    int lane = t & 63;
    int i = t >> 4;
    int c = t & 15;

    {
        int idx = t * 4;
        int qi = idx >> 6, qd = idx & 63;
        const _Float16* src = qkv + ((size_t)(b * S_ + n * BS_ + qi)) * (3 * D_) + h * DH_ + qd;
#pragma unroll
        for (int u = 0; u < 4; ++u) qs[qi][qd + u] = (float)src[u];
    }

    float acc[4] = {0.f, 0.f, 0.f, 0.f};
    float m_old = -1e30f, l = 0.f;

    for (int jj = 0; jj < 7; ++jj) {
        int kb = key_idx[n * 7 + jj];
        __syncthreads();
        {
            int idx = t * 4;
            int ri = idx >> 6, rd = idx & 63;
            const _Float16* kp = qkv + ((size_t)(b * S_ + kb * BS_ + ri)) * (3 * D_) + D_ + h * DH_ + rd;
            const _Float16* vp = kp + D_;
#pragma unroll
            for (int u = 0; u < 4; ++u) { ks[ri][rd + u] = (float)kp[u]; vs[ri][rd + u] = (float)vp[u]; }
        }
        __syncthreads();

        float s = 0.f;
#pragma unroll
        for (int d = 0; d < 64; ++d) s += qs[i][d] * ks[c][d];
        s *= SCALE_F;

        float rm = s;
#pragma unroll
        for (int off = 8; off; off >>= 1) rm = fmaxf(rm, __shfl_xor(rm, off, 64));
        float m_new = fmaxf(m_old, rm);
        float p = __expf(s - m_new);
        float rs = p;
#pragma unroll
        for (int off = 8; off; off >>= 1) rs += __shfl_xor(rs, off, 64);
        float corr = __expf(m_old - m_new);
        l = l * corr + rs;
#pragma unroll
        for (int u = 0; u < 4; ++u) acc[u] *= corr;

        int base = lane & 48;
#pragma unroll
        for (int j = 0; j < 16; ++j) {
            float pj = __shfl(p, base + j, 64);
#pragma unroll
            for (int u = 0; u < 4; ++u) acc[u] += pj * vs[j][c * 4 + u];
        }
        m_old = m_new;
    }

    float inv = 1.f / l;
    _Float16* dst = outp + ((size_t)(b * S_ + n * BS_ + i)) * D_ + h * DH_ + c * 4;
#pragma unroll
    for (int u = 0; u < 4; ++u) dst[u] = (_Float16)(acc[u] * inv);
}

// ---------------------------------------------------------------------------
// Edge attention split-K partials (qkv f16, partials fp32)
// ---------------------------------------------------------------------------
__global__ __launch_bounds__(256) void attn_edge_partial(
    const _Float16* __restrict__ qkv, float* __restrict__ pm,
    float* __restrict__ pl, float* __restrict__ pacc)
{
    int gb = blockIdx.x;
    int split = gb % NSPLIT;
    int be = gb / NSPLIT;
    int e = be & 1;
    int h = (be >> 1) % H_;
    int b = be / (2 * H_);
    int n = e ? (NB_ - 1) : 0;

    __shared__ float qs[16][65];
    __shared__ float ks[16][65];
    __shared__ float vs[16][65];

    int t = threadIdx.x;
    int lane = t & 63;
    int i = t >> 4;
    int c = t & 15;

    {
        int idx = t * 4;
        int qi = idx >> 6, qd = idx & 63;
        const _Float16* src = qkv + ((size_t)(b * S_ + n * BS_ + qi)) * (3 * D_) + h * DH_ + qd;
#pragma unroll
        for (int u = 0; u < 4; ++u) qs[qi][qd + u] = (float)src[u];
    }

    float acc[4] = {0.f, 0.f, 0.f, 0.f};
    float m_old = -1e30f, l = 0.f;

    for (int jj = 0; jj < TILES_PER_SPLIT; ++jj) {
        int kb = split * TILES_PER_SPLIT + jj;
        __syncthreads();
        {
            int idx = t * 4;
            int ri = idx >> 6, rd = idx & 63;
            const _Float16* kp = qkv + ((size_t)(b * S_ + kb * BS_ + ri)) * (3 * D_) + D_ + h * DH_ + rd;
            const _Float16* vp = kp + D_;
#pragma unroll
            for (int u = 0; u < 4; ++u) { ks[ri][rd + u] = (float)kp[u]; vs[ri][rd + u] = (float)vp[u]; }
        }
        __syncthreads();

        float s = 0.f;
#pragma unroll
        for (int d = 0; d < 64; ++d) s += qs[i][d] * ks[c][d];
        s *= SCALE_F;

        float rm = s;
#pragma unroll
        for (int off = 8; off; off >>= 1) rm = fmaxf(rm, __shfl_xor(rm, off, 64));
        float m_new = fmaxf(m_old, rm);
        float p = __expf(s - m_new);
        float rs = p;
#pragma unroll
        for (int off = 8; off; off >>= 1) rs += __shfl_xor(rs, off, 64);
        float corr = __expf(m_old - m_new);
        l = l * corr + rs;
#pragma unroll
        for (int u = 0; u < 4; ++u) acc[u] *= corr;

        int base = lane & 48;
#pragma unroll
        for (int j = 0; j < 16; ++j) {
            float pj = __shfl(p, base + j, 64);
#pragma unroll
            for (int u = 0; u < 4; ++u) acc[u] += pj * vs[j][c * 4 + u];
        }
        m_old = m_new;
    }

    int ps = (be * NSPLIT + split) * 16 + i;
    if (c == 0) { pm[ps] = m_old; pl[ps] = l; }
#pragma unroll
    for (int u = 0; u < 4; ++u) pacc[(size_t)ps * 64 + c * 4 + u] = acc[u];
}

__global__ __launch_bounds__(256) void attn_edge_combine(
    const float* __restrict__ pm, const float* __restrict__ pl,
    const float* __restrict__ pacc, _Float16* __restrict__ outp)
{
    int be = blockIdx.x;
    int e = be & 1;
    int h = (be >> 1) % H_;
    int b = be / (2 * H_);
    int n = e ? (NB_ - 1) : 0;

    int t = threadIdx.x;
    int i = t >> 4;
    int c = t & 15;

    float M = -1e30f;
#pragma unroll 4
    for (int s = 0; s < NSPLIT; ++s)
        M = fmaxf(M, pm[(be * NSPLIT + s) * 16 + i]);

    float L = 0.f;
    float acc[4] = {0.f, 0.f, 0.f, 0.f};
    for (int s = 0; s < NSPLIT; ++s) {
        int ps = (be * NSPLIT + s) * 16 + i;
        float wgt = __expf(pm[ps] - M);
        L += pl[ps] * wgt;
#pragma unroll
        for (int u = 0; u < 4; ++u) acc[u] += pacc[(size_t)ps * 64 + c * 4 + u] * wgt;
    }

    float inv = 1.f / L;
    _Float16* dst = outp + ((size_t)(b * S_ + n * BS_ + i)) * D_ + h * DH_ + c * 4;
#pragma unroll
    for (int u = 0; u < 4; ++u) dst[u] = (_Float16)(acc[u] * inv);
}

// ---------------------------------------------------------------------------
// x = LayerNorm(x + g); writes fp32 x and f16 xb
// ---------------------------------------------------------------------------
__global__ __launch_bounds__(256) void add_ln_kernel(
    float* __restrict__ x, const float* __restrict__ g,
    const float* __restrict__ gamma, const float* __restrict__ beta,
    _Float16* __restrict__ xb)
{
    int row = blockIdx.x;
    int t = threadIdx.x;
    float* xr = x + (size_t)row * D_;
    const float* gr = g + (size_t)row * D_;
    _Float16* br = xb + (size_t)row * D_;

    float v[3];
    float s = 0.f, s2 = 0.f;
#pragma unroll
    for (int r = 0; r < 3; ++r) {
        int d = t + 256 * r;
        v[r] = xr[d] + gr[d];
        s += v[r];
        s2 += v[r] * v[r];
    }
#pragma unroll
    for (int off = 32; off; off >>= 1) {
        s  += __shfl_xor(s, off, 64);
        s2 += __shfl_xor(s2, off, 64);
    }
    __shared__ float sA[4], sB[4];
    int wave = t >> 6, lane = t & 63;
    if (lane == 0) { sA[wave] = s; sB[wave] = s2; }
    __syncthreads();
    s  = sA[0] + sA[1] + sA[2] + sA[3];
    s2 = sB[0] + sB[1] + sB[2] + sB[3];
    float mean = s * (1.0f / D_);
    float var = s2 * (1.0f / D_) - mean * mean;
    float rstd = rsqrtf(var + 1e-12f);
#pragma unroll
    for (int r = 0; r < 3; ++r) {
        int d = t + 256 * r;
        float o = (v[r] - mean) * rstd * gamma[d] + beta[d];
        xr[d] = o;
        br[d] = (_Float16)o;
    }
}

// ---------------------------------------------------------------------------
__global__ __launch_bounds__(64) void head_logits(
    const float* __restrict__ x, const float* __restrict__ sw,
    const float* __restrict__ ew, float* __restrict__ sl, float* __restrict__ el)
{
    int row = blockIdx.x;
    int lane = threadIdx.x;
    const float* xr = x + (size_t)row * D_;
    float a = 0.f, e = 0.f;
    for (int d = lane; d < D_; d += 64) {
        float xv = xr[d];
        a += xv * sw[d];
        e += xv * ew[d];
    }
#pragma unroll
    for (int off = 32; off; off >>= 1) {
        a += __shfl_xor(a, off, 64);
        e += __shfl_xor(e, off, 64);
    }
    if (lane == 0) { sl[row] = a; el[row] = e; }
}

__global__ __launch_bounds__(256) void softmax_rows(
    const float* __restrict__ sl, const float* __restrict__ el,
    float* __restrict__ outp)
{
    int r = blockIdx.x;
    const float* src = (r < 2 ? sl : el) + (size_t)(r & 1) * S_;
    float* dst = outp + (r < 2 ? 0 : BT_) + (size_t)(r & 1) * S_;
    int t = threadIdx.x;
    int wave = t >> 6, lane = t & 63;
    __shared__ float sm[4], ss[4];

    float m = -1e30f;
    for (int k = t; k < S_; k += 256) m = fmaxf(m, src[k]);
#pragma unroll
    for (int off = 32; off; off >>= 1) m = fmaxf(m, __shfl_xor(m, off, 64));
    if (lane == 0) sm[wave] = m;
    __syncthreads();
    m = fmaxf(fmaxf(sm[0], sm[1]), fmaxf(sm[2], sm[3]));

    float s = 0.f;
    for (int k = t; k < S_; k += 256) s += __expf(src[k] - m);
#pragma unroll
    for (int off = 32; off; off >>= 1) s += __shfl_xor(s, off, 64);
    if (lane == 0) ss[wave] = s;
    __syncthreads();
    s = ss[0] + ss[1] + ss[2] + ss[3];

    float inv = 1.f / s;
    for (int k = t; k < S_; k += 256) dst[k] = __expf(src[k] - m) * inv;
}

// ---------------------------------------------------------------------------
// disc pool GEMV, split: grid (3 j-groups x DKS k-splits), 256 threads.
// partial[ks][j] = sum_{k in split} x0[k] * Wp[k][j]
// ---------------------------------------------------------------------------
__global__ __launch_bounds__(256) void disc_pool_partial(
    const float* __restrict__ x, const float* __restrict__ Wp,
    float* __restrict__ partial)
{
    int jb = blockIdx.x;      // 0..2
    int ks = blockIdx.y;      // 0..DKS-1
    int t = threadIdx.x;
    int j = jb * 256 + t;
    int k0 = ks * DKC;

    __shared__ float xs[DKC];
    if (t < DKC) xs[t] = x[k0 + t];   // x0 = x row 0
    __syncthreads();

    float s = 0.f;
#pragma unroll 8
    for (int kk = 0; kk < DKC; ++kk)
        s += xs[kk] * Wp[(size_t)(k0 + kk) * D_ + j];
    partial[ks * D_ + j] = s;
}

// ---------------------------------------------------------------------------
// disc finish: reduce partials + bias + tanh -> pool; 768->20->2 + softmax
// ---------------------------------------------------------------------------
__global__ __launch_bounds__(256) void disc_finish(
    const float* __restrict__ partial, const float* __restrict__ bp,
    const float* __restrict__ d1W, const float* __restrict__ d1b,
    const float* __restrict__ d2W, const float* __restrict__ d2b,
    float* __restrict__ out2)
{
    __shared__ float pool[D_];
    __shared__ float h1[20];
    int t = threadIdx.x;
    for (int j = t; j < D_; j += 256) {
        float s = bp[j];
#pragma unroll
        for (int ks = 0; ks < DKS; ++ks) s += partial[ks * D_ + j];
        pool[j] = tanhf(s);
    }
    __syncthreads();
    if (t < 20) {
        float s = d1b[t];
        for (int k = 0; k < D_; ++k) s += pool[k] * d1W[k * 20 + t];
        h1[t] = s;
    }
    __syncthreads();
    if (t == 0) {
        float d0 = d2b[0], d1v = d2b[1];
#pragma unroll
        for (int u = 0; u < 20; ++u) {
            d0  += h1[u] * d2W[u * 2 + 0];
            d1v += h1[u] * d2W[u * 2 + 1];
        }
        float m = fmaxf(d0, d1v);
        float e0 = __expf(d0 - m), e1 = __expf(d1v - m);
        float inv = 1.f / (e0 + e1);
        out2[0] = e0 * inv;
        out2[1] = e1 * inv;
    }
}

// ---------------------------------------------------------------------------
extern "C" void kernel_launch(void* const* d_in, const int* in_sizes, int n_in,
                              void* d_out, int out_size, void* d_ws, size_t ws_size,
                              hipStream_t stream)
{
    const int*   ids   = (const int*)d_in[0];
    const int*   kbi   = (const int*)d_in[1];
    const float* emb   = (const float*)d_in[2];
    const float* Wqkv  = (const float*)d_in[3];
    const float* bqkv  = (const float*)d_in[4];
    const float* Wo    = (const float*)d_in[5];
    const float* bo    = (const float*)d_in[6];
    const float* ln1g  = (const float*)d_in[7];
    const float* ln1b  = (const float*)d_in[8];
    const float* Wff1  = (const float*)d_in[9];
    const float* bff1  = (const float*)d_in[10];
    const float* Wff2  = (const float*)d_in[11];
    const float* bff2  = (const float*)d_in[12];
    const float* ln2g  = (const float*)d_in[13];
    const float* ln2b  = (const float*)d_in[14];
    const float* Wp    = (const float*)d_in[15];
    const float* bp    = (const float*)d_in[16];
    const float* sw    = (const float*)d_in[17];
    const float* ew    = (const float*)d_in[18];
    const float* d1W   = (const float*)d_in[19];
    const float* d1b   = (const float*)d_in[20];
    const float* d2W   = (const float*)d_in[21];
    const float* d2b   = (const float*)d_in[22];
    float* outp = (float*)d_out;

    // workspace carve (float units)
    float* ws   = (float*)d_ws;
    float* x    = ws;                          // 6,291,456 f32
    float* xbf  = x   + (size_t)BT_ * D_;      // f16 xb
    float* r1f  = xbf + (size_t)BT_ * D_ / 2;  // f16 qkv / f16 h
    float* abf  = r1f + (size_t)BT_ * FF_ / 2; // f16 attn out
    float* r2   = abf + (size_t)BT_ * D_ / 2;  // f32 proj/ff2 (partials early)
    float* wtf  = r2  + (size_t)BT_ * D_;      // f16 weights
    float* sl   = wtf + 7077888;
    float* el   = sl  + BT_;
    float* dpar = el  + BT_;                   // DKS * D_ disc partials

    _Float16* xb    = (_Float16*)xbf;
    _Float16* qkv16 = (_Float16*)r1f;
    _Float16* h16   = (_Float16*)r1f;
    _Float16* ab    = (_Float16*)abf;
    float* pm   = r2;
    float* pl   = r2 + NEDGE * NSPLIT * 16;
    float* pacc = pl + NEDGE * NSPLIT * 16;

    _Float16* Wt    = (_Float16*)wtf;
    _Float16* WqkvT = Wt;
    _Float16* WoT   = WqkvT + (size_t)2 * 2304 * 768;
    _Float16* Wff1T = WoT   + (size_t)2 * 768 * 768;
    _Float16* Wff2T = Wff1T + (size_t)2 * 3072 * 768;

    for (int l = 0; l < 2; ++l) {
        wconvert_kernel<<<dim3(2304/32, 768/32), 256, 0, stream>>>(
            Wqkv + (size_t)l * 768 * 2304, WqkvT + (size_t)l * 2304 * 768, 768, 2304);
        wconvert_kernel<<<dim3(768/32, 768/32), 256, 0, stream>>>(
            Wo + (size_t)l * 768 * 768, WoT + (size_t)l * 768 * 768, 768, 768);
        wconvert_kernel<<<dim3(3072/32, 768/32), 256, 0, stream>>>(
            Wff1 + (size_t)l * 768 * 3072, Wff1T + (size_t)l * 3072 * 768, 768, 3072);
        wconvert_kernel<<<dim3(768/32, 3072/32), 256, 0, stream>>>(
            Wff2 + (size_t)l * 3072 * 768, Wff2T + (size_t)l * 768 * 3072, 3072, 768);
    }

    embed_kernel<<<BT_, 256, 0, stream>>>(ids, emb, x, xb);

    for (int l = 0; l < 2; ++l) {
        gemm_f16<0,1><<<dim3(2304/128, BT_/128), 256, 0, stream>>>(
            xb, WqkvT + (size_t)l * 2304 * 768, bqkv + (size_t)l * 3 * D_,
            qkv16, BT_, 3 * D_, D_);
        attn_sparse<<<B_ * H_ * NB_, 256, 0, stream>>>(qkv16, kbi, ab);
        attn_edge_partial<<<NEDGE * NSPLIT, 256, 0, stream>>>(qkv16, pm, pl, pacc);
        attn_edge_combine<<<NEDGE, 256, 0, stream>>>(pm, pl, pacc, ab);
        gemm_f16<0,0><<<dim3(768/128, BT_/128), 256, 0, stream>>>(
            ab, WoT + (size_t)l * 768 * 768, bo + (size_t)l * D_,
            r2, BT_, D_, D_);
        add_ln_kernel<<<BT_, 256, 0, stream>>>(x, r2, ln1g + (size_t)l * D_, ln1b + (size_t)l * D_, xb);
        gemm_f16<1,1><<<dim3(3072/128, BT_/128), 256, 0, stream>>>(
            xb, Wff1T + (size_t)l * 3072 * 768, bff1 + (size_t)l * FF_,
            h16, BT_, FF_, D_);
        gemm_f16<0,0><<<dim3(768/128, BT_/128), 256, 0, stream>>>(
            h16, Wff2T + (size_t)l * 768 * 3072, bff2 + (size_t)l * D_,
            r2, BT_, D_, FF_);
        add_ln_kernel<<<BT_, 256, 0, stream>>>(x, r2, ln2g + (size_t)l * D_, ln2b + (size_t)l * D_, xb);
    }

    head_logits<<<BT_, 64, 0, stream>>>(x, sw, ew, sl, el);
    softmax_rows<<<4, 256, 0, stream>>>(sl, el, outp);
    disc_pool_partial<<<dim3(3, DKS), 256, 0, stream>>>(x, Wp, dpar);
    disc_finish<<<1, 256, 0, stream>>>(dpar, bp, d1W, d1b, d2W, d2b, outp + 2 * BT_);
}